// Round 6
// baseline (411.328 us; speedup 1.0000x reference)
//
#include <hip/hip_runtime.h>

#define NN 100000
#define NE 3200000
#define F 64
#define NR 8
#define PAD 68                 // LDS row stride (floats) for As/Bs
#define NT 1563                // node tiles = ceil(NN/64) = final buckets
#define CAPT 2560              // per-tile record capacity (mean 2048, ~11 sigma)
#define CHUNK 4000             // edges per bin block (800 blocks x 4000 = NE)

// ---------------- bf16 helpers ----------------------------------------------
__device__ __forceinline__ unsigned bf16rne(float f) {
    unsigned u = __float_as_uint(f);
    return (u + 0x7FFFu + ((u >> 16) & 1u)) >> 16;
}
__device__ __forceinline__ unsigned pk2(float a, float b) {
    return bf16rne(a) | (bf16rne(b) << 16);
}
__device__ __forceinline__ float blo(unsigned u) { return __uint_as_float(u << 16); }
__device__ __forceinline__ float bhi(unsigned u) { return __uint_as_float(u & 0xffff0000u); }

// ---------------- convert x to bf16 (row layout kept) -----------------------
__global__ __launch_bounds__(256) void convx_kernel(
    const float* __restrict__ x, unsigned* __restrict__ xh)   // xh = packed pairs
{
    int i = blockIdx.x * 256 + threadIdx.x;      // 800000 threads, elems [8i,8i+8)
    float4 a = ((const float4*)x)[2 * i];
    float4 b = ((const float4*)x)[2 * i + 1];
    uint4 o;
    o.x = pk2(a.x, a.y); o.y = pk2(a.z, a.w);
    o.z = pk2(b.x, b.y); o.w = pk2(b.z, b.w);
    ((uint4*)xh)[i] = o;
}

// ---------------- convert [root; W0..7] to bf16 -----------------------------
__global__ __launch_bounds__(256) void convw_kernel(
    const float* __restrict__ weight, const float* __restrict__ root,
    unsigned* __restrict__ wh)
{
    int i = blockIdx.x * 256 + threadIdx.x;      // 4608 threads, elems [8i,8i+8)
    if (i >= 4608) return;
    const float* src = (i < 512) ? (root + 8 * i) : (weight + 8 * i - 4096);
    float4 a = ((const float4*)src)[0];
    float4 b = ((const float4*)src)[1];
    uint4 o;
    o.x = pk2(a.x, a.y); o.y = pk2(a.z, a.w);
    o.z = pk2(b.x, b.y); o.w = pk2(b.z, b.w);
    ((uint4*)wh)[i] = o;
}

// ---------------- init per-tile cursors -------------------------------------
__global__ __launch_bounds__(256) void init_kernel(int* __restrict__ cursors) {
    int i = blockIdx.x * 256 + threadIdx.x;
    if (i < NT) cursors[i] = i * CAPT;
}

// ---------------- single-pass binning into node tiles -----------------------
// 800 blocks x 4000 edges. LDS multi-split into 1563 tile buckets, then
// cursor-reserved burst writes -> tile regions fill densely.
__global__ __launch_bounds__(256) void bin_kernel(
    const int* __restrict__ esrc, const int* __restrict__ edst,
    const int* __restrict__ etyp,
    int* __restrict__ cursors, unsigned* __restrict__ packed4)
{
    __shared__ int cur[NT];        // counts -> scatter cursor (aliased)
    __shared__ int start[NT];
    __shared__ int base2[NT];      // global_base - local_start
    __shared__ int scantmp[256];
    __shared__ unsigned g_p[CHUNK];
    __shared__ unsigned short g_t[CHUNK];

    const int t = threadIdx.x;
    const int e0 = blockIdx.x * CHUNK;

    for (int i = t; i < NT; i += 256) cur[i] = 0;
    __syncthreads();

    unsigned rp[16]; unsigned short rt[16];
#pragma unroll
    for (int j = 0; j < 16; j++) {
        int i = t + j * 256;
        if (i < CHUNK) {
            int e = e0 + i;
            unsigned s = (unsigned)esrc[e];
            unsigned d = (unsigned)edst[e];
            unsigned r = (unsigned)etyp[e];
            rt[j] = (unsigned short)(d >> 6);
            rp[j] = s | ((d & 63u) << 17) | (r << 23);
            atomicAdd(&cur[d >> 6], 1);
        }
    }
    __syncthreads();

    // blocked exclusive scan over NT counters (7 per thread)
    const int b0 = t * 7;
    int cnts[7], lsum = 0;
#pragma unroll
    for (int j = 0; j < 7; j++) {
        int idx = b0 + j;
        cnts[j] = (idx < NT) ? cur[idx] : 0;
        lsum += cnts[j];
    }
    scantmp[t] = lsum;
    __syncthreads();
    for (int off = 1; off < 256; off <<= 1) {
        int v = (t >= off) ? scantmp[t - off] : 0;
        __syncthreads();
        scantmp[t] += v;
        __syncthreads();
    }
    int run = scantmp[t] - lsum;   // exclusive base for this thread's segment
    __syncthreads();
#pragma unroll
    for (int j = 0; j < 7; j++) {
        int idx = b0 + j;
        if (idx < NT) {
            start[idx] = run;
            cur[idx] = run;
            if (cnts[j] > 0) {
                int g = atomicAdd(&cursors[idx], cnts[j]);   // reserve global run
                base2[idx] = g - run;
            }
            run += cnts[j];
        }
    }
    __syncthreads();

    // scatter into tile-grouped LDS
#pragma unroll
    for (int j = 0; j < 16; j++) {
        int i = t + j * 256;
        if (i < CHUNK) {
            int slot = atomicAdd(&cur[rt[j]], 1);
            g_p[slot] = rp[j];
            g_t[slot] = rt[j];
        }
    }
    __syncthreads();

    // burst write-out: consecutive slots in a bucket -> consecutive global addrs
#pragma unroll
    for (int j = 0; j < 16; j++) {
        int i = t + j * 256;
        if (i < CHUNK) {
            int b = g_t[i];
            packed4[base2[b] + i] = g_p[i];
        }
    }
}

// ---------------- fused: LDS counting-sort + bf16 gather-mean + GEMM --------
__global__ __launch_bounds__(256) void fused_kernel(
    const unsigned* __restrict__ xh,      // bf16 pairs [NN][32]
    const unsigned* __restrict__ packed4,
    const int* __restrict__ cursors,
    const unsigned* __restrict__ wh,      // bf16 pairs [9][2048] = [root;W0..7]
    const float* __restrict__ bias,
    float* __restrict__ out)
{
    __shared__ float As[64][PAD];
    __shared__ float Bs[64][PAD];
    __shared__ int kstart[512];
    __shared__ int kcur[512];
    __shared__ int slist[CAPT];

    const int t = threadIdx.x;
    const int tile = blockIdx.x;
    const int s0 = tile * CAPT;
    const int c = cursors[tile] - s0;

    // ---- LDS counting sort by key9 = rel*64 + dstLow ----
    kstart[t] = 0; kstart[t + 256] = 0;
    __syncthreads();
    for (int i = t; i < c; i += 256) {
        unsigned p = packed4[s0 + i];
        atomicAdd(&kstart[p >> 17], 1);
    }
    __syncthreads();
    int a0 = kstart[2 * t], a1 = kstart[2 * t + 1];
    int psum = a0 + a1;
    kcur[t] = psum;
    __syncthreads();
    for (int off = 1; off < 256; off <<= 1) {
        int v = (t >= off) ? kcur[t - off] : 0;
        __syncthreads();
        kcur[t] += v;
        __syncthreads();
    }
    int ebase = kcur[t] - psum;
    __syncthreads();
    kstart[2 * t]     = ebase;
    kstart[2 * t + 1] = ebase + a0;
    kcur[2 * t]       = ebase;
    kcur[2 * t + 1]   = ebase + a0;
    __syncthreads();
    for (int i = t; i < c; i += 256) {
        unsigned p = packed4[s0 + i];
        int slot = atomicAdd(&kcur[p >> 17], 1);
        slist[slot] = (int)(p & 0x1FFFFu);
    }
    __syncthreads();   // kcur[k] == end of run k

    // ---- GEMM ----
    const int tx = t & 15;
    const int ty = t >> 4;
    const int node0 = tile * 64;
    const int sn = t >> 2;
    const int sq = t & 3;
    const int nclamp = min(node0 + sn, NN - 1);

    float acc[4][4];
#pragma unroll
    for (int i = 0; i < 4; i++)
#pragma unroll
        for (int j = 0; j < 4; j++) acc[i][j] = 0.f;

    for (int seg = 0; seg < 9; seg++) {
        const unsigned* __restrict__ Wseg = wh + seg * 2048;   // 2048 pairs = 4096 bf16

        __syncthreads();
        // stage B: 2 x uint4 per thread (8 bf16 each), unpack to fp32 LDS
#pragma unroll
        for (int j = 0; j < 2; j++) {
            int u4 = t + j * 256;               // uint4 index 0..511
            uint4 v = ((const uint4*)Wseg)[u4];
            int g = u4 * 8;                     // element index, 8-aligned
            float* dst = &Bs[g >> 6][g & 63];
            dst[0] = blo(v.x); dst[1] = bhi(v.x);
            dst[2] = blo(v.y); dst[3] = bhi(v.y);
            dst[4] = blo(v.z); dst[5] = bhi(v.z);
            dst[6] = blo(v.w); dst[7] = bhi(v.w);
        }

        // stage A: k-chunks {4sq, 4sq+16, 4sq+32, 4sq+48} per thread
        const int k0 = sq << 2;
        if (seg == 0) {
            const unsigned* xr = xh + nclamp * 32 + (sq << 1);
            uint2 w0 = *(const uint2*)(xr);
            uint2 w1 = *(const uint2*)(xr + 8);
            uint2 w2 = *(const uint2*)(xr + 16);
            uint2 w3 = *(const uint2*)(xr + 24);
            As[k0 +  0][sn] = blo(w0.x); As[k0 +  1][sn] = bhi(w0.x);
            As[k0 +  2][sn] = blo(w0.y); As[k0 +  3][sn] = bhi(w0.y);
            As[k0 + 16][sn] = blo(w1.x); As[k0 + 17][sn] = bhi(w1.x);
            As[k0 + 18][sn] = blo(w1.y); As[k0 + 19][sn] = bhi(w1.y);
            As[k0 + 32][sn] = blo(w2.x); As[k0 + 33][sn] = bhi(w2.x);
            As[k0 + 34][sn] = blo(w2.y); As[k0 + 35][sn] = bhi(w2.y);
            As[k0 + 48][sn] = blo(w3.x); As[k0 + 49][sn] = bhi(w3.x);
            As[k0 + 50][sn] = blo(w3.y); As[k0 + 51][sn] = bhi(w3.y);
        } else {
            const int key = ((seg - 1) << 6) | sn;
            const int beg = kstart[key];
            const int end = kcur[key];
            float4 a0v = make_float4(0.f, 0.f, 0.f, 0.f);
            float4 a1v = a0v, a2v = a0v, a3v = a0v;
            for (int i = beg; i < end; i++) {
                const unsigned* xr = xh + slist[i] * 32 + (sq << 1);
                uint2 w0 = *(const uint2*)(xr);
                uint2 w1 = *(const uint2*)(xr + 8);
                uint2 w2 = *(const uint2*)(xr + 16);
                uint2 w3 = *(const uint2*)(xr + 24);
                a0v.x += blo(w0.x); a0v.y += bhi(w0.x); a0v.z += blo(w0.y); a0v.w += bhi(w0.y);
                a1v.x += blo(w1.x); a1v.y += bhi(w1.x); a1v.z += blo(w1.y); a1v.w += bhi(w1.y);
                a2v.x += blo(w2.x); a2v.y += bhi(w2.x); a2v.z += blo(w2.y); a2v.w += bhi(w2.y);
                a3v.x += blo(w3.x); a3v.y += bhi(w3.x); a3v.z += blo(w3.y); a3v.w += bhi(w3.y);
            }
            float scl = 1.0f / (float)max(end - beg, 1);
            As[k0 +  0][sn] = a0v.x * scl; As[k0 +  1][sn] = a0v.y * scl;
            As[k0 +  2][sn] = a0v.z * scl; As[k0 +  3][sn] = a0v.w * scl;
            As[k0 + 16][sn] = a1v.x * scl; As[k0 + 17][sn] = a1v.y * scl;
            As[k0 + 18][sn] = a1v.z * scl; As[k0 + 19][sn] = a1v.w * scl;
            As[k0 + 32][sn] = a2v.x * scl; As[k0 + 33][sn] = a2v.y * scl;
            As[k0 + 34][sn] = a2v.z * scl; As[k0 + 35][sn] = a2v.w * scl;
            As[k0 + 48][sn] = a3v.x * scl; As[k0 + 49][sn] = a3v.y * scl;
            As[k0 + 50][sn] = a3v.z * scl; As[k0 + 51][sn] = a3v.w * scl;
        }
        __syncthreads();

#pragma unroll 8
        for (int k = 0; k < 64; k++) {
            float4 a = *(const float4*)&As[k][ty << 2];
            float4 b = *(const float4*)&Bs[k][tx << 2];
            acc[0][0] = fmaf(a.x, b.x, acc[0][0]);
            acc[0][1] = fmaf(a.x, b.y, acc[0][1]);
            acc[0][2] = fmaf(a.x, b.z, acc[0][2]);
            acc[0][3] = fmaf(a.x, b.w, acc[0][3]);
            acc[1][0] = fmaf(a.y, b.x, acc[1][0]);
            acc[1][1] = fmaf(a.y, b.y, acc[1][1]);
            acc[1][2] = fmaf(a.y, b.z, acc[1][2]);
            acc[1][3] = fmaf(a.y, b.w, acc[1][3]);
            acc[2][0] = fmaf(a.z, b.x, acc[2][0]);
            acc[2][1] = fmaf(a.z, b.y, acc[2][1]);
            acc[2][2] = fmaf(a.z, b.z, acc[2][2]);
            acc[2][3] = fmaf(a.z, b.w, acc[2][3]);
            acc[3][0] = fmaf(a.w, b.x, acc[3][0]);
            acc[3][1] = fmaf(a.w, b.y, acc[3][1]);
            acc[3][2] = fmaf(a.w, b.z, acc[3][2]);
            acc[3][3] = fmaf(a.w, b.w, acc[3][3]);
        }
    }

    float4 bv = *(const float4*)(bias + (tx << 2));
#pragma unroll
    for (int i = 0; i < 4; i++) {
        int node = node0 + (ty << 2) + i;
        if (node < NN) {
            float4 o = make_float4(acc[i][0] + bv.x, acc[i][1] + bv.y,
                                   acc[i][2] + bv.z, acc[i][3] + bv.w);
            *(float4*)(out + (size_t)node * F + (tx << 2)) = o;
        }
    }
}

extern "C" void kernel_launch(void* const* d_in, const int* in_sizes, int n_in,
                              void* d_out, int out_size, void* d_ws, size_t ws_size,
                              hipStream_t stream) {
    const float* x    = (const float*)d_in[0];
    const int*   ei   = (const int*)d_in[1];   // [2, NE]: row0 = src, row1 = dst
    const int*   et   = (const int*)d_in[2];
    const float* wgt  = (const float*)d_in[3];
    const float* root = (const float*)d_in[4];
    const float* bias = (const float*)d_in[5];
    float*       out  = (float*)d_out;

    // workspace layout (16B-aligned sections)
    int*      cursors = (int*)d_ws;                                 // [2048]
    unsigned* packed4 = (unsigned*)((char*)d_ws + 8192);            // [NT*CAPT] 16.0 MB
    unsigned* xh      = (unsigned*)((char*)packed4 + (size_t)NT * CAPT * 4);  // 12.8 MB (bf16 pairs)
    unsigned* wh      = (unsigned*)((char*)xh + (size_t)NN * F * 2);          // 73.7 KB

    convx_kernel<<<3125, 256, 0, stream>>>(x, xh);
    convw_kernel<<<18, 256, 0, stream>>>(wgt, root, wh);
    init_kernel<<<(NT + 255) / 256, 256, 0, stream>>>(cursors);
    bin_kernel<<<NE / CHUNK, 256, 0, stream>>>(ei, ei + NE, et, cursors, packed4);
    fused_kernel<<<NT, 256, 0, stream>>>(xh, packed4, cursors, wh, bias, out);
}